// Round 2
// baseline (685.642 us; speedup 1.0000x reference)
//
#include <hip/hip_runtime.h>

#define MROWS 8192
#define NCOLS 128
#define KSTEP 128
#define BM    16    // rows per block -> grid 512 = 2 blocks/CU on the big GEMMs
#define LDT   136   // LDS row stride in bf16 elems: 272 B -> bank stride 4 (2-way, free), 16B-aligned

using f32x4  = __attribute__((ext_vector_type(4))) float;
using bf16x8 = __attribute__((ext_vector_type(8))) short;
using u32x4  = __attribute__((ext_vector_type(4))) unsigned int;
using u32x2  = __attribute__((ext_vector_type(2))) unsigned int;

__device__ __forceinline__ unsigned short f2bf(float f) {
    unsigned int u = __float_as_uint(f);
    u += 0x7fffu + ((u >> 16) & 1u);   // RNE
    return (unsigned short)(u >> 16);
}
__device__ __forceinline__ unsigned int pk2(float a, float b) {
    return (unsigned int)f2bf(a) | ((unsigned int)f2bf(b) << 16);
}

// C[M,128] = A[M,K](fp32) @ B[K,128], B stored transposed bf16: Bt[c][k], row stride ldb.
// BM=16 output rows per block, full 128 cols, full K. 256 threads = 4 waves (1m x 4n),
// each wave: 16 rows x 32 cols -> 2 f32x4 acc. Grid = M/16 = 512 -> 2 blocks/CU:
// when one block drains vmcnt at its barrier, the other block's waves keep the
// HBM pipe and MFMA pipe busy (implicit wave-level overlap).
// OUTMODE 0: bf16 transposed   out[c][r]              (Tt)
// OUTMODE 1: bf16 transposed   out[c][r] = v*filt[r]  (Rt, filt fused)
// OUTMODE 2: fp32 row-major    out[r][c]              (final output)
template <int OUTMODE>
__global__ __launch_bounds__(256, 2) void gemm_tall(
    const float* __restrict__ A,
    const unsigned short* __restrict__ Bt,
    void* __restrict__ out,
    const float* __restrict__ filt,
    int Kdim, int ldb)
{
    __shared__ __align__(16) unsigned short As[BM * LDT];
    __shared__ __align__(16) unsigned short Bs[128 * LDT];

    const int tid  = threadIdx.x;
    const int lane = tid & 63;
    const int wn   = (tid >> 6) * 32;   // wave col base: 0/32/64/96
    const int lrow = lane & 15;
    const int lq   = lane >> 4;
    const int m0   = blockIdx.x * BM;

    // coalesced staging decomposition (per 128-wide K-step)
    const int arow = tid >> 4;          // 0..15, 16 thr/row, 8 fp32 each (512 B contig per row)
    const int ak   = (tid & 15) * 8;
    const int brow = tid >> 1;          // 0..127, 2 thr/row, 64 bf16 (128 B) each
    const int bk   = (tid & 1) * 64;

    const float*          Ap = A  + (size_t)(m0 + arow) * Kdim + ak;
    const unsigned short* Bp = Bt + (size_t)brow * ldb + bk;

    f32x4 a0[2], a1[2];
    u32x4 b0[8], b1[8];

#define LDG(a, b, k0) do { \
        a[0] = *(const f32x4*)(Ap + (k0));              \
        a[1] = *(const f32x4*)(Ap + (k0) + 4);          \
        const unsigned short* bp_ = Bp + (k0);          \
        _Pragma("unroll")                               \
        for (int i_ = 0; i_ < 8; ++i_)                  \
            b[i_] = *(const u32x4*)(bp_ + i_ * 8);      \
    } while (0)

#define STG(a, b) do { \
        u32x4 av_;                                      \
        av_.x = pk2(a[0].x, a[0].y);                    \
        av_.y = pk2(a[0].z, a[0].w);                    \
        av_.z = pk2(a[1].x, a[1].y);                    \
        av_.w = pk2(a[1].z, a[1].w);                    \
        *(u32x4*)&As[arow * LDT + ak] = av_;            \
        _Pragma("unroll")                               \
        for (int i_ = 0; i_ < 8; ++i_)                  \
            *(u32x4*)&Bs[brow * LDT + bk + i_ * 8] = b[i_]; \
    } while (0)

    f32x4 acc0 = {0.f, 0.f, 0.f, 0.f};
    f32x4 acc1 = {0.f, 0.f, 0.f, 0.f};

    auto COMPUTE = [&]() {
#pragma unroll
        for (int kk = 0; kk < 4; ++kk) {
            const int ko = kk * 32 + lq * 8;
            bf16x8 af  = *(bf16x8*)&As[lrow * LDT + ko];
            bf16x8 bf0 = *(bf16x8*)&Bs[(wn + lrow) * LDT + ko];
            bf16x8 bf1 = *(bf16x8*)&Bs[(wn + 16 + lrow) * LDT + ko];
            acc0 = __builtin_amdgcn_mfma_f32_16x16x32_bf16(af, bf0, acc0, 0, 0, 0);
            acc1 = __builtin_amdgcn_mfma_f32_16x16x32_bf16(af, bf1, acc1, 0, 0, 0);
        }
    };

    const int iters = Kdim / KSTEP;     // 64 (big GEMMs) or 2 (GEMM1) — always even
    LDG(a0, b0, 0);
    LDG(a1, b1, KSTEP);
    STG(a0, b0);
    __syncthreads();

    for (int it = 0; it < iters; it += 2) {
        if (it + 2 < iters) LDG(a0, b0, (it + 2) * KSTEP);   // prefetch step it+2
        COMPUTE();                                           // step it
        __syncthreads();
        STG(a1, b1);                                         // step it+1 -> LDS
        __syncthreads();
        if (it + 3 < iters) LDG(a1, b1, (it + 3) * KSTEP);   // prefetch step it+3
        COMPUTE();                                           // step it+1
        if (it + 2 < iters) {
            __syncthreads();
            STG(a0, b0);                                     // step it+2 -> LDS
            __syncthreads();
        }
    }
#undef LDG
#undef STG

    const int r = m0 + lq * 4;
    if (OUTMODE == 2) {
        float* O = (float*)out;
#pragma unroll
        for (int nt = 0; nt < 2; ++nt) {
            const int c = wn + nt * 16 + lrow;
            const f32x4 v = nt ? acc1 : acc0;
#pragma unroll
            for (int e = 0; e < 4; ++e)
                O[(size_t)(r + e) * NCOLS + c] = v[e];
        }
    } else {
        unsigned short* O = (unsigned short*)out;
        f32x4 v0 = acc0, v1 = acc1;
        if (OUTMODE == 1) {
            const f32x4 fl = *(const f32x4*)&filt[r];   // r is a multiple of 4, 16B-aligned
            v0 *= fl;
            v1 *= fl;
        }
        u32x2 o;
        o.x = pk2(v0.x, v0.y); o.y = pk2(v0.z, v0.w);
        *(u32x2*)&O[(size_t)(wn + lrow) * MROWS + r] = o;
        o.x = pk2(v1.x, v1.y); o.y = pk2(v1.z, v1.w);
        *(u32x2*)&O[(size_t)(wn + 16 + lrow) * MROWS + r] = o;
    }
}

// Wt[c][k] = bf16(W[k][c]) : 256x128 fp32 -> transposed bf16
__global__ void convert_w(const float* __restrict__ W, unsigned short* __restrict__ Wt) {
    int idx = blockIdx.x * 256 + threadIdx.x;   // 32768 total
    int k = idx >> 7, c = idx & 127;
    Wt[c * 256 + k] = f2bf(W[idx]);
}

extern "C" void kernel_launch(void* const* d_in, const int* in_sizes, int n_in,
                              void* d_out, int out_size, void* d_ws, size_t ws_size,
                              hipStream_t stream) {
    const float* features     = (const float*)d_in[0];
    const float* wavelets     = (const float*)d_in[1];
    const float* wavelets_inv = (const float*)d_in[2];
    const float* W            = (const float*)d_in[3];
    const float* filt         = (const float*)d_in[4];
    float* outp = (float*)d_out;

    char* ws = (char*)d_ws;
    unsigned short* Tt = (unsigned short*)ws;                              // 2 MB  Tt[c][r]
    unsigned short* Rt = (unsigned short*)(ws + (size_t)2 * 1024 * 1024);  // 2 MB  Rt[c][r]
    unsigned short* Wt = (unsigned short*)(ws + (size_t)4 * 1024 * 1024);  // 64 KB Wt[c][k]

    // 1) W -> Wt (bf16, transposed)
    convert_w<<<128, 256, 0, stream>>>(W, Wt);
    // 2) Tt = (features @ W)^T          full-K, direct bf16 transposed output
    gemm_tall<0><<<512, 256, 0, stream>>>(features,     Wt, (void*)Tt,   nullptr, 256,  256);
    // 3) Rt = (filt ⊙ (wavelets_inv @ T))^T   full-K, filt fused in epilogue
    gemm_tall<1><<<512, 256, 0, stream>>>(wavelets_inv, Tt, (void*)Rt,   filt,    8192, 8192);
    // 4) out = wavelets @ R             full-K, fp32 row-major output
    gemm_tall<2><<<512, 256, 0, stream>>>(wavelets,     Rt, (void*)outp, nullptr, 8192, 8192);
}